// Round 16
// baseline (64.075 us; speedup 1.0000x reference)
//
#include <hip/hip_runtime.h>
#include <hip/hip_bf16.h>

// GraphLSTM fused kernel for MI355X — R16: unique-slot writes, 2 launches.
// R15 (56.9us): TLP saturated; remaining costs are the scatter apparatus
// (partial-zero + 279K atomics + reduce) and the xt transpose. This round:
//  - per-edge folded result stored to res[e*8+b] (32B contiguous, 8 lanes):
//    conflict-free by construction -> NO atomics, NO zeroing, NO privatization.
//  - reduce kernel uses the sorted-dst structure: thread (n,b) binary-searches
//    CSR bounds in dst_idx[MN,E) and sums res over the contiguous run + self.
//  - x gathered directly from (B,D,MN) (L2-resident 256KB) -> prep deleted.
// Two launches total. Edge read path + lb(256,8) + grid 2048 = R15 exactly.

#define MN 1024
#define BB 8

__device__ __forceinline__ float fsig(float x) {
    return __builtin_amdgcn_rcpf(1.0f + __expf(-x));
}
__device__ __forceinline__ float ftanh(float x) {
    float t = fminf(fmaxf(2.0f * x, -30.0f), 30.0f);   // avoid inf/inf
    float e = __expf(t);
    return (e - 1.0f) * __builtin_amdgcn_rcpf(e + 1.0f);
}
__device__ __forceinline__ float rl(float v, int idx) {
    return __int_as_float(__builtin_amdgcn_readlane(__float_as_int(v), idx));
}

struct WRegs {
    float4 wi0, wi1, wg0, wg1, wo0, wo1;   // 24 VGPR
    float  bI, bG, bO;                     // 3 VGPR (pairs combined at load)
};

__device__ __forceinline__ void loadW(WRegs& r, int e, int lane,
        const float* __restrict__ W, const float* __restrict__ b_ih,
        const float* __restrict__ b_hh) {
    const float* We = W + (size_t)e * 2048 + lane * 8;
    r.wi0 = *(const float4*)(We);
    r.wi1 = *(const float4*)(We + 4);
    r.wg0 = *(const float4*)(We + 1024);
    r.wg1 = *(const float4*)(We + 1028);
    r.wo0 = *(const float4*)(We + 1536);
    r.wo1 = *(const float4*)(We + 1540);
    const float* bi = b_ih + (size_t)e * 256 + lane;
    const float* bh = b_hh + (size_t)e * 256 + lane;
    r.bI = bi[0]   + bh[0];
    r.bG = bi[128] + bh[128];
    r.bO = bi[192] + bh[192];
}

// Compute one edge; fold over lanes; store 8 batch values to res[e*8+0..7].
__device__ __forceinline__ void computeEdge(const WRegs& r, float xreg,
        int e, float ew, float cw, float* __restrict__ res, int lane) {
    float s[BB];
#pragma unroll
    for (int b = 0; b < BB; ++b) {
        float x0 = rl(xreg, b * 8 + 0), x1 = rl(xreg, b * 8 + 1);
        float x2 = rl(xreg, b * 8 + 2), x3 = rl(xreg, b * 8 + 3);
        float x4 = rl(xreg, b * 8 + 4), x5 = rl(xreg, b * 8 + 5);
        float x6 = rl(xreg, b * 8 + 6), x7 = rl(xreg, b * 8 + 7);
        float pi = r.bI, pg = r.bG, po = r.bO;
        pi = fmaf(r.wi0.x, x0, pi); pg = fmaf(r.wg0.x, x0, pg); po = fmaf(r.wo0.x, x0, po);
        pi = fmaf(r.wi0.y, x1, pi); pg = fmaf(r.wg0.y, x1, pg); po = fmaf(r.wo0.y, x1, po);
        pi = fmaf(r.wi0.z, x2, pi); pg = fmaf(r.wg0.z, x2, pg); po = fmaf(r.wo0.z, x2, po);
        pi = fmaf(r.wi0.w, x3, pi); pg = fmaf(r.wg0.w, x3, pg); po = fmaf(r.wo0.w, x3, po);
        pi = fmaf(r.wi1.x, x4, pi); pg = fmaf(r.wg1.x, x4, pg); po = fmaf(r.wo1.x, x4, po);
        pi = fmaf(r.wi1.y, x5, pi); pg = fmaf(r.wg1.y, x5, pg); po = fmaf(r.wo1.y, x5, po);
        pi = fmaf(r.wi1.z, x6, pi); pg = fmaf(r.wg1.z, x6, pg); po = fmaf(r.wo1.z, x6, po);
        pi = fmaf(r.wi1.w, x7, pi); pg = fmaf(r.wg1.w, x7, pg); po = fmaf(r.wo1.w, x7, po);
        float c = fsig(pi) * ftanh(pg);
        float h = fsig(po) * ftanh(c);
        s[b] = cw * h;
    }
    // Batch-folding reduction over 64 lanes (Σ_h), 10 shuffles total.
    float u[4];
#pragma unroll
    for (int k = 0; k < 4; ++k) {
        float keep = (lane & 32) ? s[k + 4] : s[k];
        float send = (lane & 32) ? s[k]     : s[k + 4];
        u[k] = keep + __shfl_xor(send, 32, 64);
    }
    float v[2];
#pragma unroll
    for (int k = 0; k < 2; ++k) {
        float keep = (lane & 16) ? u[k + 2] : u[k];
        float send = (lane & 16) ? u[k]     : u[k + 2];
        v[k] = keep + __shfl_xor(send, 16, 64);
    }
    float keep = (lane & 8) ? v[1] : v[0];
    float send = (lane & 8) ? v[0] : v[1];
    float t = keep + __shfl_xor(send, 8, 64);
    t += __shfl_xor(t, 4, 64);
    t += __shfl_xor(t, 2, 64);
    t += __shfl_xor(t, 1, 64);
    if ((lane & 7) == 0) {
        int b = lane >> 3;
        res[e * BB + b] = ew * t;   // unique slot: plain store, no conflict
    }
}

__global__ __launch_bounds__(256, 8) void edge_kernel(
        const float* __restrict__ x,       // (B, D, MN) original layout
        const float* __restrict__ edge_w,  // (E)
        const float* __restrict__ W,       // (E, 256, 8)
        const float* __restrict__ b_ih,    // (E, 256)
        const float* __restrict__ b_hh,    // (E, 256)
        const float* __restrict__ conv_w,  // (1, 64)
        const int*   __restrict__ src_idx,
        float* __restrict__ res,           // (E, 8) unique slots
        int E) {
    int lane = threadIdx.x & 63;
    int nw = gridDim.x * 4;
    int wid = blockIdx.x * 4 + (threadIdx.x >> 6);
    int e = __builtin_amdgcn_readfirstlane(wid);
    if (e >= E) return;
    float cw = conv_w[lane];
    // Per-lane (b,d) gather offset into original x layout.
    int xoff = (lane >> 3) * (8 * MN) + (lane & 7) * MN;

    int   srcC = src_idx[e];
    float ewC  = edge_w[e];

    while (true) {
        int eN = e + nw;
        bool hasN = (eN < E);
        int srcN = 0; float ewN = 0.0f;
        if (hasN) { srcN = src_idx[eN]; ewN = edge_w[eN]; }

        // Current edge burst + compute (8 waves/SIMD hide the wait).
        WRegs A;
        loadW(A, e, lane, W, b_ih, b_hh);
        float xA = x[xoff + srcC];         // 1 dword/lane, L2-resident gather
        computeEdge(A, xA, e, ewC, cw, res, lane);

        if (!hasN) break;
        e = eN; srcC = srcN; ewC = ewN;
    }
}

// Reduce: thread (n,b) sums self-edge + the contiguous dst-run [lo,hi) found
// by binary search in the sorted dst range [MN, E); adds conv_b.
__global__ void reduce_kernel(const float* __restrict__ res,
                              const int* __restrict__ dst_idx,
                              const float* __restrict__ conv_b,
                              float* __restrict__ out, int E) {
    int tid = blockIdx.x * 256 + threadIdx.x;   // 8192 threads
    int n = tid >> 3;
    int b = tid & 7;
    // lower_bound(n) and lower_bound(n+1) over dst_idx[MN..E)
    int l = MN, r = E;
    while (l < r) { int m = (l + r) >> 1; if (dst_idx[m] < n) l = m + 1; else r = m; }
    int lo = l;
    r = E;
    while (l < r) { int m = (l + r) >> 1; if (dst_idx[m] < n + 1) l = m + 1; else r = m; }
    int hi = l;
    float s = conv_b[0] + res[n * BB + b];      // self edge e == n
    for (int e = lo; e < hi; ++e) s += res[e * BB + b];
    out[b * MN + n] = s;
}

extern "C" void kernel_launch(void* const* d_in, const int* in_sizes, int n_in,
                              void* d_out, int out_size, void* d_ws, size_t ws_size,
                              hipStream_t stream) {
    const float* x      = (const float*)d_in[0];
    const float* edge_w = (const float*)d_in[1];
    const float* W_ih   = (const float*)d_in[2];
    const float* b_ih   = (const float*)d_in[3];
    const float* b_hh   = (const float*)d_in[4];
    const float* conv_w = (const float*)d_in[5];
    const float* conv_b = (const float*)d_in[6];
    const int* src_idx  = (const int*)d_in[7];
    const int* dst_idx  = (const int*)d_in[8];
    int E = in_sizes[1];

    float* res = (float*)d_ws;      // E*8 floats ~= 1.1 MB
    float* out = (float*)d_out;     // 8192 floats

    // 2048 blocks = 8/CU resident = 32 waves/CU.
    edge_kernel<<<2048, 256, 0, stream>>>(x, edge_w, W_ih, b_ih, b_hh,
                                          conv_w, src_idx, res, E);

    reduce_kernel<<<32, 256, 0, stream>>>(res, dst_idx, conv_b, out, E);
}